// Round 9
// baseline (240.499 us; speedup 1.0000x reference)
//
#include <hip/hip_runtime.h>
#include <hip/hip_bf16.h>
#include <cstdint>

// B=2, T=2048, C=1024, H=16, HD=64, M=256, S=2560. fp32 inputs (proven R3-R6).

typedef __bf16 bf16x8_t __attribute__((ext_vector_type(8)));
typedef __bf16 bf16x4_t __attribute__((ext_vector_type(4)));
typedef float f32x4_t __attribute__((ext_vector_type(4)));

__device__ __forceinline__ f32x4_t mfma16(bf16x8_t a, bf16x8_t b, f32x4_t c) {
    return __builtin_amdgcn_mfma_f32_16x16x32_bf16(a, b, c, 0, 0, 0);
}

__device__ __forceinline__ void gl2lds16(const void* g, void* l) {
    __builtin_amdgcn_global_load_lds(
        (__attribute__((address_space(1))) uint32_t*)(uintptr_t)g,
        (__attribute__((address_space(3))) uint32_t*)l, 16, 0, 0);
}

// arena element offsets (bf16), in setup_inputs order; total 9458704
#define OFF_X   0
#define OFF_FWD 4194304
#define OFF_REV 4718592
#define OFF_WQ  5242880
#define OFF_WK  6291456
#define OFF_WV  7340032
#define OFF_WO  8388608
#define OFF_GW  9437184
#define OFF_GB  9453568
#define OFF_CW  9453584
#define OFF_CB  9457680
#define N_TOT   9458704

// ---------------------------------------------------------------------------
// Fused convert: all 11 fp32 inputs -> one contiguous bf16 arena.
// ---------------------------------------------------------------------------
__global__ __launch_bounds__(256) void conv_all_kernel(
    const void* p0, const void* p1, const void* p2, const void* p3,
    const void* p4, const void* p5, const void* p6, const void* p7,
    const void* p8, const void* p9, const void* p10,
    __hip_bfloat16* __restrict__ arena)
{
    const int i = (blockIdx.x * 256 + threadIdx.x) * 4;
    if (i >= N_TOT) return;
    const void* src; int off;
    if      (i < OFF_FWD) { src = p0;  off = OFF_X;   }
    else if (i < OFF_REV) { src = p1;  off = OFF_FWD; }
    else if (i < OFF_WQ)  { src = p2;  off = OFF_REV; }
    else if (i < OFF_WK)  { src = p3;  off = OFF_WQ;  }
    else if (i < OFF_WV)  { src = p4;  off = OFF_WK;  }
    else if (i < OFF_WO)  { src = p5;  off = OFF_WV;  }
    else if (i < OFF_GW)  { src = p6;  off = OFF_WO;  }
    else if (i < OFF_GB)  { src = p7;  off = OFF_GW;  }
    else if (i < OFF_CW)  { src = p8;  off = OFF_GB;  }
    else if (i < OFF_CB)  { src = p9;  off = OFF_CW;  }
    else                  { src = p10; off = OFF_CB;  }
    const int j = i - off;
    const float4 f = *(const float4*)((const float*)src + j);
    arena[i + 0] = __float2bfloat16(f.x);
    arena[i + 1] = __float2bfloat16(f.y);
    arena[i + 2] = __float2bfloat16(f.z);
    arena[i + 3] = __float2bfloat16(f.w);
}

// ---------------------------------------------------------------------------
// GEMM core: C[m][n] = sum_k A[m][k]*B[n][k]; K=1024. 128x128 tile, BK=32,
// 256 threads, DOUBLE-BUFFERED LDS.
// ---------------------------------------------------------------------------
__device__ __forceinline__ void gemm_core(
    const __hip_bfloat16* __restrict__ A, const __hip_bfloat16* __restrict__ B,
    void* __restrict__ C, int ldc, int f32o, int arow0, int brow0,
    __hip_bfloat16* As, __hip_bfloat16* Bs)   // each 2*128*32 elems
{
    const int tid  = threadIdx.x;
    const int lane = tid & 63;
    const int wid  = tid >> 6;
    const int q4   = lane >> 4;
    const int c16  = lane & 15;
    const int wm   = (wid >> 1) * 64;
    const int wn   = (wid & 1) * 64;
    const int c0 = tid;
    const int c1 = tid + 256;
    const __hip_bfloat16* gA0 = A + (size_t)(arow0 + (c0 >> 2)) * 1024 + ((c0 & 3) << 3);
    const __hip_bfloat16* gA1 = A + (size_t)(arow0 + (c1 >> 2)) * 1024 + ((c1 & 3) << 3);
    const __hip_bfloat16* gB0 = B + (size_t)(brow0 + (c0 >> 2)) * 1024 + ((c0 & 3) << 3);
    const __hip_bfloat16* gB1 = B + (size_t)(brow0 + (c1 >> 2)) * 1024 + ((c1 & 3) << 3);

    f32x4_t acc[4][4];
#pragma unroll
    for (int i = 0; i < 4; ++i)
#pragma unroll
        for (int j = 0; j < 4; ++j)
#pragma unroll
            for (int r = 0; r < 4; ++r) acc[i][j][r] = 0.0f;

    // prologue: stage K-step 0 into buffer 0
    gl2lds16(gA0, As + c0 * 8);
    gl2lds16(gA1, As + c1 * 8);
    gl2lds16(gB0, Bs + c0 * 8);
    gl2lds16(gB1, Bs + c1 * 8);

    for (int it = 0; it < 32; ++it) {
        __hip_bfloat16* curA = As + (it & 1) * 4096;
        __hip_bfloat16* curB = Bs + (it & 1) * 4096;
        __syncthreads();            // drains buffer(it) loads; prev reads done
        if (it < 31) {              // prefetch buffer(it+1) BEFORE compute
            const int nk = (it + 1) * 32;
            __hip_bfloat16* nA = As + ((it + 1) & 1) * 4096;
            __hip_bfloat16* nB = Bs + ((it + 1) & 1) * 4096;
            gl2lds16(gA0 + nk, nA + c0 * 8);
            gl2lds16(gA1 + nk, nA + c1 * 8);
            gl2lds16(gB0 + nk, nB + c0 * 8);
            gl2lds16(gB1 + nk, nB + c1 * 8);
        }
        bf16x8_t af[4], bfr[4];
#pragma unroll
        for (int i = 0; i < 4; ++i)
            af[i] = *(const bf16x8_t*)&curA[(wm + i * 16 + c16) * 32 + q4 * 8];
#pragma unroll
        for (int j = 0; j < 4; ++j)
            bfr[j] = *(const bf16x8_t*)&curB[(wn + j * 16 + c16) * 32 + q4 * 8];
#pragma unroll
        for (int i = 0; i < 4; ++i)
#pragma unroll
            for (int j = 0; j < 4; ++j)
                acc[i][j] = mfma16(af[i], bfr[j], acc[i][j]);
    }
#pragma unroll
    for (int i = 0; i < 4; ++i) {
        const int mg = arow0 + wm + i * 16 + q4 * 4;
#pragma unroll
        for (int j = 0; j < 4; ++j) {
            const int ng = brow0 + wn + j * 16 + c16;
#pragma unroll
            for (int r = 0; r < 4; ++r) {
                const size_t idx = (size_t)(mg + r) * ldc + ng;
                if (f32o) ((float*)C)[idx] = acc[i][j][r];
                else ((__hip_bfloat16*)C)[idx] = __float2bfloat16(acc[i][j][r]);
            }
        }
    }
}

// Fused QK + V^T launch: 896 uniform-cost blocks (each 128x128xK=1024).
// XCD-aware swizzle (T1): id=(bx&7)*112+(bx>>3).
// Q-trim: Q columns for memory rows (4096..5119) are never read.
//   id <  512: QK x-rows:   arow 0..31,  brow 0..15 (full Q+K cols)
//   id <  576: QK mem-rows: arow 32..39, brow 8..15 (K cols only)
//   else     : Vt = Wv @ [x;fwd;rev]^T  (1024x5120,  8x40 tiles)
__global__ __launch_bounds__(256) void qkv_kernel(
    const __hip_bfloat16* __restrict__ x, const __hip_bfloat16* __restrict__ Wqk,
    const __hip_bfloat16* __restrict__ Wv,
    __hip_bfloat16* __restrict__ QK, __hip_bfloat16* __restrict__ Vt)
{
    __shared__ __align__(16) __hip_bfloat16 As[2 * 128 * 32];
    __shared__ __align__(16) __hip_bfloat16 Bs[2 * 128 * 32];
    int id = (blockIdx.x & 7) * 112 + (blockIdx.x >> 3);   // XCD swizzle
    if (id < 512)
        gemm_core(x, Wqk, QK, 2048, 0, (id >> 4) * 128, (id & 15) * 128, As, Bs);
    else if (id < 576) {
        id -= 512;
        gemm_core(x, Wqk, QK, 2048, 0, (32 + (id >> 3)) * 128, (8 + (id & 7)) * 128, As, Bs);
    } else {
        id -= 576;
        gemm_core(Wv, x, Vt, 5120, 0, (id & 7) * 128, (id >> 3) * 128, As, Bs);
    }
}

// 1D grid (256) + XCD swizzle: each XCD owns one brow panel of Wo.
__global__ __launch_bounds__(256) void gemm_bt_kernel(
    const __hip_bfloat16* __restrict__ A, const __hip_bfloat16* __restrict__ B,
    void* __restrict__ C, int ldc, int f32o)
{
    __shared__ __align__(16) __hip_bfloat16 As[2 * 128 * 32];
    __shared__ __align__(16) __hip_bfloat16 Bs[2 * 128 * 32];
    const int swz = (blockIdx.x & 7) * 32 + (blockIdx.x >> 3);  // XCD swizzle
    const int arow = swz & 31;
    const int brow = swz >> 5;
    gemm_core(A, B, C, ldc, f32o, arow * 128, brow * 128, As, Bs);
}

// ---------------------------------------------------------------------------
// Flash attention, R16 = R15 + gate fused into the prologue (gate_kernel and
// the G round-trip eliminated -> one fewer launch).
// Gate prologue: per wave, 32 MFMA with A = gw[h] broadcast to all 16 rows
// (every output row = gw[h].Q[col]), B = the wave's 16 Q rows (full 1024
// cols). Same dot products / k-order as the old gate_kernel -> numerically
// identical. sigmoid, then 4 __shfl to move gate from q=c16 layout to
// q=q4*4+r layout. Runs under the K(0) staging latency.
// Rest identical to R15 (62->60.3 us verified): Ks[2] dbuf + Vs + swizzled
// Plds = 32768 B, 2 barriers/tile, MFMA row-sums, setprio, exp2-folded
// scale, __launch_bounds__(256,4).
// ---------------------------------------------------------------------------
__global__ __launch_bounds__(256, 4) void attn_kernel(
    const __hip_bfloat16* __restrict__ QK,
    const __hip_bfloat16* __restrict__ Vt,
    const __hip_bfloat16* __restrict__ gw,
    const __hip_bfloat16* __restrict__ gb,
    __hip_bfloat16* __restrict__ Y)
{
    __shared__ __align__(16) __hip_bfloat16 Ks[2][64 * 64];   // 16384 B
    __shared__ __align__(16) __hip_bfloat16 Vs[64 * 64];      //  8192 B
    __shared__ __align__(16) __hip_bfloat16 Plds[4][16 * 64]; //  8192 B
    const int flat = blockIdx.x;          // 0..1023
    const int bh   = flat & 31;           // pin bh's K/V to one XCD
    const int tIdx = 31 - (flat >> 5);    // long blocks first
    const int b    = bh >> 4;
    const int h    = bh & 15;
    const int tid  = threadIdx.x;
    const int wid  = tid >> 6;
    const int lane = tid & 63;
    const int q4   = lane >> 4;
    const int c16  = lane & 15;
    const int rowbase = tIdx * 64 + wid * 16;

    const int nCausal = tIdx + 1;
    const int nTiles  = nCausal + 8;
    auto kvRow = [&](int tile) -> int {
        if (tile < nCausal) return b * 2048 + tile * 64;
        const int mi = (tile - nCausal) * 64;
        return (mi < 256) ? 4096 + b * 256 + mi : 4608 + b * 256 + (mi - 256);
    };

    const int srow0 = tid >> 3,         sch0 = (tid & 7) ^ (srow0 & 7);
    const int srow1 = (tid + 256) >> 3, sch1 = (tid & 7) ^ (srow1 & 7);
    const int sw0 = (q4 ^ (c16 & 7)) * 8;
    const int sw1 = ((q4 + 4) ^ (c16 & 7)) * 8;
    const __hip_bfloat16* Kbase = QK + 1024 + h * 64;  // K cols of fused buffer

    // prologue A: stage K(0) into Ks[0] (latency covered by gate compute)
    {
        const int vr0 = kvRow(0);
        gl2lds16(Kbase + (size_t)(vr0 + srow0) * 2048 + sch0 * 8, &Ks[0][tid * 8]);
        gl2lds16(Kbase + (size_t)(vr0 + srow1) * 2048 + sch1 * 8, &Ks[0][(tid + 256) * 8]);
    }

    // prologue B: fused gate. A = gw[h] broadcast (all rows identical),
    // B = Q rows of this wave -> out[*][col=c16] = gw[h].Q[q=c16].
    float gate[4];
    {
        const __hip_bfloat16* qg  = QK + (size_t)(b * 2048 + rowbase + c16) * 2048 + q4 * 8;
        const __hip_bfloat16* gwp = gw + (size_t)h * 1024 + q4 * 8;
        f32x4_t gacc = {0.0f, 0.0f, 0.0f, 0.0f};
#pragma unroll
        for (int kk = 0; kk < 32; ++kk) {
            const bf16x8_t ga = *(const bf16x8_t*)(gwp + kk * 32);
            const bf16x8_t qb = *(const bf16x8_t*)(qg + kk * 32);
            gacc = mfma16(ga, qb, gacc);
        }
        const float gbh = __bfloat162float(gb[h]);
        const float gself = 1.0f / (1.0f + __expf(-(gacc[0] + gbh)));
#pragma unroll
        for (int r = 0; r < 4; ++r)
            gate[r] = __shfl(gself, (lane & 48) | (q4 * 4 + r), 64);
    }

    const __hip_bfloat16* qrow = QK + (size_t)(b * 2048 + rowbase + c16) * 2048 + h * 64;
    const bf16x8_t qa0 = *(const bf16x8_t*)(qrow + q4 * 8);
    const bf16x8_t qa1 = *(const bf16x8_t*)(qrow + 32 + q4 * 8);

    bf16x8_t ones;
#pragma unroll
    for (int i = 0; i < 8; ++i) ones[i] = (__bf16)1.0f;

    f32x4_t acc[4];
    f32x4_t rsC = {0.0f, 0.0f, 0.0f, 0.0f};
    f32x4_t rsM = {0.0f, 0.0f, 0.0f, 0.0f};
#pragma unroll
    for (int fp = 0; fp < 4; ++fp)
#pragma unroll
        for (int r = 0; r < 4; ++r) acc[fp][r] = 0.0f;

    const float SCL = 0.18033688f;   // 0.125 * log2(e)

    for (int tile = 0; tile < nTiles; ++tile) {
        const int cur = tile & 1;
        const int vr  = kvRow(tile);
        __syncthreads();   // barrier1: all waves done reading Vs(tile-1);
                           // K(tile) already drained at prev barrier2/prologue
        // issue V(tile) and prefetch K(tile+1); both covered by QK+softmax below
        gl2lds16(Vt + (size_t)(h * 64 + srow0) * 5120 + vr + sch0 * 8, &Vs[tid * 8]);
        gl2lds16(Vt + (size_t)(h * 64 + srow1) * 5120 + vr + sch1 * 8, &Vs[(tid + 256) * 8]);
        if (tile + 1 < nTiles) {
            const int nr = kvRow(tile + 1);
            gl2lds16(Kbase + (size_t)(nr + srow0) * 2048 + sch0 * 8, &Ks[cur ^ 1][tid * 8]);
            gl2lds16(Kbase + (size_t)(nr + srow1) * 2048 + sch1 * 8, &Ks[cur ^ 1][(tid + 256) * 8]);
        }
        const bool isMem  = (tile >= nCausal);
        const bool isDiag = (tile == nCausal - 1);
        bf16x8_t kb0[4], kb1[4];
#pragma unroll
        for (int f = 0; f < 4; ++f) {
            kb0[f] = *(const bf16x8_t*)&Ks[cur][(f * 16 + c16) * 64 + sw0];
            kb1[f] = *(const bf16x8_t*)&Ks[cur][(f * 16 + c16) * 64 + sw1];
        }
        f32x4_t sc[4];
        __builtin_amdgcn_s_setprio(1);
#pragma unroll
        for (int f = 0; f < 4; ++f) {
            f32x4_t z = {0.0f, 0.0f, 0.0f, 0.0f};
            z = mfma16(qa0, kb0[f], z);
            z = mfma16(qa1, kb1[f], z);
            sc[f] = z;
        }
        __builtin_amdgcn_s_setprio(0);
#pragma unroll
        for (int f = 0; f < 4; ++f)
#pragma unroll
            for (int r = 0; r < 4; ++r) {
                float p = __builtin_amdgcn_exp2f(sc[f][r] * SCL);
                if (isDiag) {
                    const int sg = f * 16 + c16;                 // s within tile
                    if (sg > wid * 16 + q4 * 4 + r) p = 0.0f;    // q within tile
                }
                if (isMem) p *= gate[r];    // gate mem contribution only
                const int prow = q4 * 4 + r;
                const int pcol = f * 16 + c16;
                Plds[wid][prow * 64 + (((pcol >> 3) ^ (prow & 7)) << 3) + (pcol & 7)] =
                    __float2bfloat16(p);
            }
        __syncthreads();   // barrier2: V(tile) + K(tile+1) landed (covered above)
        bf16x8_t vb0[4], vb1[4];
#pragma unroll
        for (int f = 0; f < 4; ++f) {
            vb0[f] = *(const bf16x8_t*)&Vs[(f * 16 + c16) * 64 + sw0];
            vb1[f] = *(const bf16x8_t*)&Vs[(f * 16 + c16) * 64 + sw1];
        }
        const bf16x8_t pa0 = *(const bf16x8_t*)&Plds[wid][c16 * 64 + sw0];
        const bf16x8_t pa1 = *(const bf16x8_t*)&Plds[wid][c16 * 64 + sw1];
        __builtin_amdgcn_s_setprio(1);
        if (isMem) {
            rsM = mfma16(pa0, ones, rsM);
            rsM = mfma16(pa1, ones, rsM);
        } else {
            rsC = mfma16(pa0, ones, rsC);
            rsC = mfma16(pa1, ones, rsC);
        }
#pragma unroll
        for (int fp = 0; fp < 4; ++fp) {
            acc[fp] = mfma16(pa0, vb0[fp], acc[fp]);
            acc[fp] = mfma16(pa1, vb1[fp], acc[fp]);
        }
        __builtin_amdgcn_s_setprio(0);
    }

    // denominator: rsC (ungated causal) + rsM/gate (rsM accumulated gated P)
    float inv[4];
#pragma unroll
    for (int r = 0; r < 4; ++r)
        inv[r] = gate[r] / fmaf(gate[r], rsC[r], rsM[r]);
#pragma unroll
    for (int fp = 0; fp < 4; ++fp)
#pragma unroll
        for (int r = 0; r < 4; ++r) {
            const int tg = rowbase + q4 * 4 + r;
            Y[(size_t)(b * 2048 + tg) * 1024 + h * 64 + fp * 16 + c16] =
                __float2bfloat16(acc[fp][r] * inv[r]);
        }
}

// ---------------------------------------------------------------------------
// Canon depthwise causal conv (K=4) + bias. R16: 4 timesteps x 4 channels
// per thread -- the 7 input rows are loaded ONCE and produce 4 outputs
// (read traffic 75 -> 27 MB; per-element math identical to R15).
// grid: 2*512*256 threads = 1024 blocks x 256.
// ---------------------------------------------------------------------------
__global__ __launch_bounds__(256) void canon_kernel(
    const __hip_bfloat16* __restrict__ Yin, const __hip_bfloat16* __restrict__ cw,
    const __hip_bfloat16* __restrict__ cb, __hip_bfloat16* __restrict__ Yout)
{
    const int gid = blockIdx.x * 256 + threadIdx.x;   // 0..262143
    const int cc  = (gid & 255) * 4;                  // channel chunk base
    const int t4  = ((gid >> 8) & 511) * 4;           // time chunk base
    const int b   = gid >> 17;
    const size_t base = ((size_t)(b * 2048 + t4)) * 1024 + cc;

    bf16x4_t y[7];
#pragma unroll
    for (int m = 0; m < 7; ++m) {
        if (t4 - 3 + m >= 0)
            y[m] = *(const bf16x4_t*)(Yin + base + (ptrdiff_t)(m - 3) * 1024);
        else {
            y[m][0] = (__bf16)0.0f; y[m][1] = (__bf16)0.0f;
            y[m][2] = (__bf16)0.0f; y[m][3] = (__bf16)0.0f;
        }
    }
    const bf16x8_t w01 = *(const bf16x8_t*)(cw + cc * 4);
    const bf16x8_t w23 = *(const bf16x8_t*)(cw + cc * 4 + 8);
    const bf16x4_t bb  = *(const bf16x4_t*)(cb + cc);

#pragma unroll
    for (int k = 0; k < 4; ++k) {
        float a[4];
#pragma unroll
        for (int i = 0; i < 4; ++i) a[i] = (float)y[k + 3][i] + (float)bb[i];
#pragma unroll
        for (int j = 0; j < 4; ++j) {
            a[0] += (float)y[k + j][0] * (float)w01[j];
            a[1] += (float)y[k + j][1] * (float)w01[4 + j];
            a[2] += (float)y[k + j][2] * (float)w23[j];
            a[3] += (float)y[k + j][3] * (float)w23[4 + j];
        }
        bf16x4_t o;
#pragma unroll
        for (int i = 0; i < 4; ++i) o[i] = (__bf16)a[i];
        *(bf16x4_t*)(Yout + base + (size_t)k * 1024) = o;
    }
}

// ---------------------------------------------------------------------------
extern "C" void kernel_launch(void* const* d_in, const int* in_sizes, int n_in,
                              void* d_out, int out_size, void* d_ws, size_t ws_size,
                              hipStream_t stream)
{
    char* ws = (char*)d_ws;
    const size_t MB = 1ull << 20;
    if (ws_size < 50 * MB) return;  // canary

    __hip_bfloat16* arena = (__hip_bfloat16*)ws;              // 18.05 MB
    __hip_bfloat16* QK    = (__hip_bfloat16*)(ws + 19 * MB);  // 20 MB (5120x2048)
    __hip_bfloat16* Vt    = (__hip_bfloat16*)(ws + 39 * MB);  // 10 MB (1024x5120)
    __hip_bfloat16* Y1    = (__hip_bfloat16*)ws;              // reuse x region
    __hip_bfloat16* Y2    = QK;                               // reuse after attention

    const dim3 blk(256);
    conv_all_kernel<<<dim3((N_TOT / 4 + 255) / 256), blk, 0, stream>>>(
        d_in[0], d_in[1], d_in[2], d_in[3], d_in[4], d_in[5], d_in[6],
        d_in[7], d_in[8], d_in[9], d_in[10], arena);

    const __hip_bfloat16* xB  = arena + OFF_X;   // [x;fwd;rev] = 5120 rows
    const __hip_bfloat16* WqB = arena + OFF_WQ;  // [Wq;Wk] = 2048 contiguous rows
    const __hip_bfloat16* WvB = arena + OFF_WV;
    const __hip_bfloat16* WoB = arena + OFF_WO;

    // fused QK (x:full, mem:K-only) + V^T in one 896-block launch
    qkv_kernel<<<dim3(896), blk, 0, stream>>>(xB, WqB, WvB, QK, Vt);
    // attention with fused gate (gate_kernel + G round-trip eliminated)
    attn_kernel<<<dim3(1024), blk, 0, stream>>>(QK, Vt, arena + OFF_GW, arena + OFF_GB, Y1);
    canon_kernel<<<dim3(1024), blk, 0, stream>>>(Y1, arena + OFF_CW, arena + OFF_CB, Y2);
    // output projection (fp32 out)
    gemm_bt_kernel<<<dim3(256), blk, 0, stream>>>(Y2, WoB, d_out, 1024, 1);
}

// Round 10
// 231.056 us; speedup vs baseline: 1.0409x; 1.0409x over previous
//
#include <hip/hip_runtime.h>
#include <hip/hip_bf16.h>
#include <cstdint>

// B=2, T=2048, C=1024, H=16, HD=64, M=256, S=2560. fp32 inputs (proven R3-R6).

typedef __bf16 bf16x8_t __attribute__((ext_vector_type(8)));
typedef __bf16 bf16x4_t __attribute__((ext_vector_type(4)));
typedef float f32x4_t __attribute__((ext_vector_type(4)));

__device__ __forceinline__ f32x4_t mfma16(bf16x8_t a, bf16x8_t b, f32x4_t c) {
    return __builtin_amdgcn_mfma_f32_16x16x32_bf16(a, b, c, 0, 0, 0);
}

__device__ __forceinline__ void gl2lds16(const void* g, void* l) {
    __builtin_amdgcn_global_load_lds(
        (__attribute__((address_space(1))) uint32_t*)(uintptr_t)g,
        (__attribute__((address_space(3))) uint32_t*)l, 16, 0, 0);
}

// arena element offsets (bf16), in setup_inputs order; total 9458704
#define OFF_X   0
#define OFF_FWD 4194304
#define OFF_REV 4718592
#define OFF_WQ  5242880
#define OFF_WK  6291456
#define OFF_WV  7340032
#define OFF_WO  8388608
#define OFF_GW  9437184
#define OFF_GB  9453568
#define OFF_CW  9453584
#define OFF_CB  9457680
#define N_TOT   9458704

// ---------------------------------------------------------------------------
// Fused convert: all 11 fp32 inputs -> one contiguous bf16 arena.
// ---------------------------------------------------------------------------
__global__ __launch_bounds__(256) void conv_all_kernel(
    const void* p0, const void* p1, const void* p2, const void* p3,
    const void* p4, const void* p5, const void* p6, const void* p7,
    const void* p8, const void* p9, const void* p10,
    __hip_bfloat16* __restrict__ arena)
{
    const int i = (blockIdx.x * 256 + threadIdx.x) * 4;
    if (i >= N_TOT) return;
    const void* src; int off;
    if      (i < OFF_FWD) { src = p0;  off = OFF_X;   }
    else if (i < OFF_REV) { src = p1;  off = OFF_FWD; }
    else if (i < OFF_WQ)  { src = p2;  off = OFF_REV; }
    else if (i < OFF_WK)  { src = p3;  off = OFF_WQ;  }
    else if (i < OFF_WV)  { src = p4;  off = OFF_WK;  }
    else if (i < OFF_WO)  { src = p5;  off = OFF_WV;  }
    else if (i < OFF_GW)  { src = p6;  off = OFF_WO;  }
    else if (i < OFF_GB)  { src = p7;  off = OFF_GW;  }
    else if (i < OFF_CW)  { src = p8;  off = OFF_GB;  }
    else if (i < OFF_CB)  { src = p9;  off = OFF_CW;  }
    else                  { src = p10; off = OFF_CB;  }
    const int j = i - off;
    const float4 f = *(const float4*)((const float*)src + j);
    arena[i + 0] = __float2bfloat16(f.x);
    arena[i + 1] = __float2bfloat16(f.y);
    arena[i + 2] = __float2bfloat16(f.z);
    arena[i + 3] = __float2bfloat16(f.w);
}

// ---------------------------------------------------------------------------
// GEMM core: C[m][n] = sum_k A[m][k]*B[n][k]; K=1024. 128x128 tile, BK=32,
// 256 threads, DOUBLE-BUFFERED LDS.
// ---------------------------------------------------------------------------
__device__ __forceinline__ void gemm_core(
    const __hip_bfloat16* __restrict__ A, const __hip_bfloat16* __restrict__ B,
    void* __restrict__ C, int ldc, int f32o, int arow0, int brow0,
    __hip_bfloat16* As, __hip_bfloat16* Bs)   // each 2*128*32 elems
{
    const int tid  = threadIdx.x;
    const int lane = tid & 63;
    const int wid  = tid >> 6;
    const int q4   = lane >> 4;
    const int c16  = lane & 15;
    const int wm   = (wid >> 1) * 64;
    const int wn   = (wid & 1) * 64;
    const int c0 = tid;
    const int c1 = tid + 256;
    const __hip_bfloat16* gA0 = A + (size_t)(arow0 + (c0 >> 2)) * 1024 + ((c0 & 3) << 3);
    const __hip_bfloat16* gA1 = A + (size_t)(arow0 + (c1 >> 2)) * 1024 + ((c1 & 3) << 3);
    const __hip_bfloat16* gB0 = B + (size_t)(brow0 + (c0 >> 2)) * 1024 + ((c0 & 3) << 3);
    const __hip_bfloat16* gB1 = B + (size_t)(brow0 + (c1 >> 2)) * 1024 + ((c1 & 3) << 3);

    f32x4_t acc[4][4];
#pragma unroll
    for (int i = 0; i < 4; ++i)
#pragma unroll
        for (int j = 0; j < 4; ++j)
#pragma unroll
            for (int r = 0; r < 4; ++r) acc[i][j][r] = 0.0f;

    // prologue: stage K-step 0 into buffer 0
    gl2lds16(gA0, As + c0 * 8);
    gl2lds16(gA1, As + c1 * 8);
    gl2lds16(gB0, Bs + c0 * 8);
    gl2lds16(gB1, Bs + c1 * 8);

    for (int it = 0; it < 32; ++it) {
        __hip_bfloat16* curA = As + (it & 1) * 4096;
        __hip_bfloat16* curB = Bs + (it & 1) * 4096;
        __syncthreads();            // drains buffer(it) loads; prev reads done
        if (it < 31) {              // prefetch buffer(it+1) BEFORE compute
            const int nk = (it + 1) * 32;
            __hip_bfloat16* nA = As + ((it + 1) & 1) * 4096;
            __hip_bfloat16* nB = Bs + ((it + 1) & 1) * 4096;
            gl2lds16(gA0 + nk, nA + c0 * 8);
            gl2lds16(gA1 + nk, nA + c1 * 8);
            gl2lds16(gB0 + nk, nB + c0 * 8);
            gl2lds16(gB1 + nk, nB + c1 * 8);
        }
        bf16x8_t af[4], bfr[4];
#pragma unroll
        for (int i = 0; i < 4; ++i)
            af[i] = *(const bf16x8_t*)&curA[(wm + i * 16 + c16) * 32 + q4 * 8];
#pragma unroll
        for (int j = 0; j < 4; ++j)
            bfr[j] = *(const bf16x8_t*)&curB[(wn + j * 16 + c16) * 32 + q4 * 8];
#pragma unroll
        for (int i = 0; i < 4; ++i)
#pragma unroll
            for (int j = 0; j < 4; ++j)
                acc[i][j] = mfma16(af[i], bfr[j], acc[i][j]);
    }
#pragma unroll
    for (int i = 0; i < 4; ++i) {
        const int mg = arow0 + wm + i * 16 + q4 * 4;
#pragma unroll
        for (int j = 0; j < 4; ++j) {
            const int ng = brow0 + wn + j * 16 + c16;
#pragma unroll
            for (int r = 0; r < 4; ++r) {
                const size_t idx = (size_t)(mg + r) * ldc + ng;
                if (f32o) ((float*)C)[idx] = acc[i][j][r];
                else ((__hip_bfloat16*)C)[idx] = __float2bfloat16(acc[i][j][r]);
            }
        }
    }
}

// Fused QK + V^T launch: 896 uniform-cost blocks (each 128x128xK=1024).
// XCD-aware swizzle (T1): id=(bx&7)*112+(bx>>3).
// Q-trim: Q columns for memory rows (4096..5119) are never read.
//   id <  512: QK x-rows:   arow 0..31,  brow 0..15 (full Q+K cols)
//   id <  576: QK mem-rows: arow 32..39, brow 8..15 (K cols only)
//   else     : Vt = Wv @ [x;fwd;rev]^T  (1024x5120,  8x40 tiles)
__global__ __launch_bounds__(256) void qkv_kernel(
    const __hip_bfloat16* __restrict__ x, const __hip_bfloat16* __restrict__ Wqk,
    const __hip_bfloat16* __restrict__ Wv,
    __hip_bfloat16* __restrict__ QK, __hip_bfloat16* __restrict__ Vt)
{
    __shared__ __align__(16) __hip_bfloat16 As[2 * 128 * 32];
    __shared__ __align__(16) __hip_bfloat16 Bs[2 * 128 * 32];
    int id = (blockIdx.x & 7) * 112 + (blockIdx.x >> 3);   // XCD swizzle
    if (id < 512)
        gemm_core(x, Wqk, QK, 2048, 0, (id >> 4) * 128, (id & 15) * 128, As, Bs);
    else if (id < 576) {
        id -= 512;
        gemm_core(x, Wqk, QK, 2048, 0, (32 + (id >> 3)) * 128, (8 + (id & 7)) * 128, As, Bs);
    } else {
        id -= 576;
        gemm_core(Wv, x, Vt, 5120, 0, (id & 7) * 128, (id >> 3) * 128, As, Bs);
    }
}

// 1D grid (256) + XCD swizzle: each XCD owns one brow panel of Wo.
__global__ __launch_bounds__(256) void gemm_bt_kernel(
    const __hip_bfloat16* __restrict__ A, const __hip_bfloat16* __restrict__ B,
    void* __restrict__ C, int ldc, int f32o)
{
    __shared__ __align__(16) __hip_bfloat16 As[2 * 128 * 32];
    __shared__ __align__(16) __hip_bfloat16 Bs[2 * 128 * 32];
    const int swz = (blockIdx.x & 7) * 32 + (blockIdx.x >> 3);  // XCD swizzle
    const int arow = swz & 31;
    const int brow = swz >> 5;
    gemm_core(A, B, C, ldc, f32o, arow * 128, brow * 128, As, Bs);
}

// ---------------------------------------------------------------------------
// Gate via MFMA: one wave per 16 rows; G[row][h] = sigmoid(Q.gw^T + gb)
// (R17: restored -- fusing this into attn (R16) caused a 28 MB FETCH blowup:
// every head re-read full-width Q rows on its own XCD. One-pass here = 8 MB.)
// ---------------------------------------------------------------------------
__global__ __launch_bounds__(64) void gate_kernel(
    const __hip_bfloat16* __restrict__ QK, const __hip_bfloat16* __restrict__ gw,
    const __hip_bfloat16* __restrict__ gb, float* __restrict__ G)
{
    const int base = blockIdx.x * 16;
    const int lane = threadIdx.x;
    const int q4   = lane >> 4;
    const int c16  = lane & 15;
    f32x4_t acc = {0.0f, 0.0f, 0.0f, 0.0f};
    const __hip_bfloat16* qrow = QK + (size_t)(base + c16) * 2048 + q4 * 8;
    const __hip_bfloat16* wrow = gw + (size_t)c16 * 1024 + q4 * 8;
#pragma unroll
    for (int kk = 0; kk < 32; ++kk) {
        const bf16x8_t a = *(const bf16x8_t*)(qrow + kk * 32);
        const bf16x8_t w = *(const bf16x8_t*)(wrow + kk * 32);
        acc = mfma16(a, w, acc);
    }
    const float bias = __bfloat162float(gb[c16]);
#pragma unroll
    for (int r = 0; r < 4; ++r) {
        const int row = base + q4 * 4 + r;
        G[(size_t)row * 16 + c16] = 1.0f / (1.0f + __expf(-(acc[r] + bias)));
    }
}

// ---------------------------------------------------------------------------
// Flash attention, R17 = exact R15 attn (60.3 us, FETCH 15.4 MB verified).
// Ks[2] dbuf (16K) + Vs single (8K) + swizzled Plds (8K) = 32768 B;
// two barriers per tile, V(t)+K(t+1) staged between them under QK+softmax;
// MFMA row-sums (rsC/rsM gated-mem algebra), setprio, exp2-folded scale,
// __launch_bounds__(256,4), VGPR 64.
// ---------------------------------------------------------------------------
__global__ __launch_bounds__(256, 4) void attn_kernel(
    const __hip_bfloat16* __restrict__ QK,
    const __hip_bfloat16* __restrict__ Vt,
    const float* __restrict__ G, __hip_bfloat16* __restrict__ Y)
{
    __shared__ __align__(16) __hip_bfloat16 Ks[2][64 * 64];   // 16384 B
    __shared__ __align__(16) __hip_bfloat16 Vs[64 * 64];      //  8192 B
    __shared__ __align__(16) __hip_bfloat16 Plds[4][16 * 64]; //  8192 B
    const int flat = blockIdx.x;          // 0..1023
    const int bh   = flat & 31;           // pin bh's K/V to one XCD
    const int tIdx = 31 - (flat >> 5);    // long blocks first
    const int b    = bh >> 4;
    const int h    = bh & 15;
    const int tid  = threadIdx.x;
    const int wid  = tid >> 6;
    const int lane = tid & 63;
    const int q4   = lane >> 4;
    const int c16  = lane & 15;
    const int rowbase = tIdx * 64 + wid * 16;

    const __hip_bfloat16* qrow = QK + (size_t)(b * 2048 + rowbase + c16) * 2048 + h * 64;
    const bf16x8_t qa0 = *(const bf16x8_t*)(qrow + q4 * 8);
    const bf16x8_t qa1 = *(const bf16x8_t*)(qrow + 32 + q4 * 8);

    bf16x8_t ones;
#pragma unroll
    for (int i = 0; i < 8; ++i) ones[i] = (__bf16)1.0f;

    float gate[4];
    f32x4_t acc[4];
    f32x4_t rsC = {0.0f, 0.0f, 0.0f, 0.0f};
    f32x4_t rsM = {0.0f, 0.0f, 0.0f, 0.0f};
#pragma unroll
    for (int fp = 0; fp < 4; ++fp)
#pragma unroll
        for (int r = 0; r < 4; ++r) acc[fp][r] = 0.0f;
#pragma unroll
    for (int r = 0; r < 4; ++r)
        gate[r] = G[(size_t)(b * 2048 + rowbase + q4 * 4 + r) * 16 + h];

    const int nCausal = tIdx + 1;
    const int nTiles  = nCausal + 8;
    auto kvRow = [&](int tile) -> int {
        if (tile < nCausal) return b * 2048 + tile * 64;
        const int mi = (tile - nCausal) * 64;
        return (mi < 256) ? 4096 + b * 256 + mi : 4608 + b * 256 + (mi - 256);
    };

    const int srow0 = tid >> 3,         sch0 = (tid & 7) ^ (srow0 & 7);
    const int srow1 = (tid + 256) >> 3, sch1 = (tid & 7) ^ (srow1 & 7);
    const int sw0 = (q4 ^ (c16 & 7)) * 8;
    const int sw1 = ((q4 + 4) ^ (c16 & 7)) * 8;
    const __hip_bfloat16* Kbase = QK + 1024 + h * 64;  // K cols of fused buffer

    // prologue: stage K(0) into Ks[0]
    {
        const int vr0 = kvRow(0);
        gl2lds16(Kbase + (size_t)(vr0 + srow0) * 2048 + sch0 * 8, &Ks[0][tid * 8]);
        gl2lds16(Kbase + (size_t)(vr0 + srow1) * 2048 + sch1 * 8, &Ks[0][(tid + 256) * 8]);
    }

    const float SCL = 0.18033688f;   // 0.125 * log2(e)

    for (int tile = 0; tile < nTiles; ++tile) {
        const int cur = tile & 1;
        const int vr  = kvRow(tile);
        __syncthreads();   // barrier1: all waves done reading Vs(tile-1);
                           // K(tile) already drained at prev barrier2/prologue
        // issue V(tile) and prefetch K(tile+1); both covered by QK+softmax below
        gl2lds16(Vt + (size_t)(h * 64 + srow0) * 5120 + vr + sch0 * 8, &Vs[tid * 8]);
        gl2lds16(Vt + (size_t)(h * 64 + srow1) * 5120 + vr + sch1 * 8, &Vs[(tid + 256) * 8]);
        if (tile + 1 < nTiles) {
            const int nr = kvRow(tile + 1);
            gl2lds16(Kbase + (size_t)(nr + srow0) * 2048 + sch0 * 8, &Ks[cur ^ 1][tid * 8]);
            gl2lds16(Kbase + (size_t)(nr + srow1) * 2048 + sch1 * 8, &Ks[cur ^ 1][(tid + 256) * 8]);
        }
        const bool isMem  = (tile >= nCausal);
        const bool isDiag = (tile == nCausal - 1);
        bf16x8_t kb0[4], kb1[4];
#pragma unroll
        for (int f = 0; f < 4; ++f) {
            kb0[f] = *(const bf16x8_t*)&Ks[cur][(f * 16 + c16) * 64 + sw0];
            kb1[f] = *(const bf16x8_t*)&Ks[cur][(f * 16 + c16) * 64 + sw1];
        }
        f32x4_t sc[4];
        __builtin_amdgcn_s_setprio(1);
#pragma unroll
        for (int f = 0; f < 4; ++f) {
            f32x4_t z = {0.0f, 0.0f, 0.0f, 0.0f};
            z = mfma16(qa0, kb0[f], z);
            z = mfma16(qa1, kb1[f], z);
            sc[f] = z;
        }
        __builtin_amdgcn_s_setprio(0);
#pragma unroll
        for (int f = 0; f < 4; ++f)
#pragma unroll
            for (int r = 0; r < 4; ++r) {
                float p = __builtin_amdgcn_exp2f(sc[f][r] * SCL);
                if (isDiag) {
                    const int sg = f * 16 + c16;                 // s within tile
                    if (sg > wid * 16 + q4 * 4 + r) p = 0.0f;    // q within tile
                }
                if (isMem) p *= gate[r];    // gate mem contribution only
                const int prow = q4 * 4 + r;
                const int pcol = f * 16 + c16;
                Plds[wid][prow * 64 + (((pcol >> 3) ^ (prow & 7)) << 3) + (pcol & 7)] =
                    __float2bfloat16(p);
            }
        __syncthreads();   // barrier2: V(tile) + K(tile+1) landed (covered above)
        bf16x8_t vb0[4], vb1[4];
#pragma unroll
        for (int f = 0; f < 4; ++f) {
            vb0[f] = *(const bf16x8_t*)&Vs[(f * 16 + c16) * 64 + sw0];
            vb1[f] = *(const bf16x8_t*)&Vs[(f * 16 + c16) * 64 + sw1];
        }
        const bf16x8_t pa0 = *(const bf16x8_t*)&Plds[wid][c16 * 64 + sw0];
        const bf16x8_t pa1 = *(const bf16x8_t*)&Plds[wid][c16 * 64 + sw1];
        __builtin_amdgcn_s_setprio(1);
        if (isMem) {
            rsM = mfma16(pa0, ones, rsM);
            rsM = mfma16(pa1, ones, rsM);
        } else {
            rsC = mfma16(pa0, ones, rsC);
            rsC = mfma16(pa1, ones, rsC);
        }
#pragma unroll
        for (int fp = 0; fp < 4; ++fp) {
            acc[fp] = mfma16(pa0, vb0[fp], acc[fp]);
            acc[fp] = mfma16(pa1, vb1[fp], acc[fp]);
        }
        __builtin_amdgcn_s_setprio(0);
    }

    // denominator: rsC (ungated causal) + rsM/gate (rsM accumulated gated P)
    float inv[4];
#pragma unroll
    for (int r = 0; r < 4; ++r)
        inv[r] = gate[r] / fmaf(gate[r], rsC[r], rsM[r]);
#pragma unroll
    for (int fp = 0; fp < 4; ++fp)
#pragma unroll
        for (int r = 0; r < 4; ++r) {
            const int tg = rowbase + q4 * 4 + r;
            Y[(size_t)(b * 2048 + tg) * 1024 + h * 64 + fp * 16 + c16] =
                __float2bfloat16(acc[fp][r] * inv[r]);
        }
}

// ---------------------------------------------------------------------------
// Canon depthwise causal conv (K=4) + bias. R16-verified: 4 timesteps x 4
// channels per thread -- 7 input rows loaded once produce 4 outputs
// (read traffic 75 -> 27 MB; per-element math identical).
// ---------------------------------------------------------------------------
__global__ __launch_bounds__(256) void canon_kernel(
    const __hip_bfloat16* __restrict__ Yin, const __hip_bfloat16* __restrict__ cw,
    const __hip_bfloat16* __restrict__ cb, __hip_bfloat16* __restrict__ Yout)
{
    const int gid = blockIdx.x * 256 + threadIdx.x;   // 0..262143
    const int cc  = (gid & 255) * 4;                  // channel chunk base
    const int t4  = ((gid >> 8) & 511) * 4;           // time chunk base
    const int b   = gid >> 17;
    const size_t base = ((size_t)(b * 2048 + t4)) * 1024 + cc;

    bf16x4_t y[7];
#pragma unroll
    for (int m = 0; m < 7; ++m) {
        if (t4 - 3 + m >= 0)
            y[m] = *(const bf16x4_t*)(Yin + base + (ptrdiff_t)(m - 3) * 1024);
        else {
            y[m][0] = (__bf16)0.0f; y[m][1] = (__bf16)0.0f;
            y[m][2] = (__bf16)0.0f; y[m][3] = (__bf16)0.0f;
        }
    }
    const bf16x8_t w01 = *(const bf16x8_t*)(cw + cc * 4);
    const bf16x8_t w23 = *(const bf16x8_t*)(cw + cc * 4 + 8);
    const bf16x4_t bb  = *(const bf16x4_t*)(cb + cc);

#pragma unroll
    for (int k = 0; k < 4; ++k) {
        float a[4];
#pragma unroll
        for (int i = 0; i < 4; ++i) a[i] = (float)y[k + 3][i] + (float)bb[i];
#pragma unroll
        for (int j = 0; j < 4; ++j) {
            a[0] += (float)y[k + j][0] * (float)w01[j];
            a[1] += (float)y[k + j][1] * (float)w01[4 + j];
            a[2] += (float)y[k + j][2] * (float)w23[j];
            a[3] += (float)y[k + j][3] * (float)w23[4 + j];
        }
        bf16x4_t o;
#pragma unroll
        for (int i = 0; i < 4; ++i) o[i] = (__bf16)a[i];
        *(bf16x4_t*)(Yout + base + (size_t)k * 1024) = o;
    }
}

// ---------------------------------------------------------------------------
extern "C" void kernel_launch(void* const* d_in, const int* in_sizes, int n_in,
                              void* d_out, int out_size, void* d_ws, size_t ws_size,
                              hipStream_t stream)
{
    char* ws = (char*)d_ws;
    const size_t MB = 1ull << 20;
    if (ws_size < 50 * MB) return;  // canary

    __hip_bfloat16* arena = (__hip_bfloat16*)ws;              // 18.05 MB
    __hip_bfloat16* QK    = (__hip_bfloat16*)(ws + 19 * MB);  // 20 MB (5120x2048)
    __hip_bfloat16* Vt    = (__hip_bfloat16*)(ws + 39 * MB);  // 10 MB (1024x5120)
    float*          G     = (float*)(ws + 49 * MB);           // 256 KB
    __hip_bfloat16* Y1    = (__hip_bfloat16*)ws;              // reuse x region
    __hip_bfloat16* Y2    = QK;                               // reuse after attention

    const dim3 blk(256);
    conv_all_kernel<<<dim3((N_TOT / 4 + 255) / 256), blk, 0, stream>>>(
        d_in[0], d_in[1], d_in[2], d_in[3], d_in[4], d_in[5], d_in[6],
        d_in[7], d_in[8], d_in[9], d_in[10], arena);

    const __hip_bfloat16* xB  = arena + OFF_X;   // [x;fwd;rev] = 5120 rows
    const __hip_bfloat16* WqB = arena + OFF_WQ;  // [Wq;Wk] = 2048 contiguous rows
    const __hip_bfloat16* WvB = arena + OFF_WV;
    const __hip_bfloat16* WoB = arena + OFF_WO;

    // fused QK (x:full, mem:K-only) + V^T in one 896-block launch
    qkv_kernel<<<dim3(896), blk, 0, stream>>>(xB, WqB, WvB, QK, Vt);
    gate_kernel<<<dim3(256), dim3(64), 0, stream>>>(QK, arena + OFF_GW, arena + OFF_GB, G);
    attn_kernel<<<dim3(1024), blk, 0, stream>>>(QK, Vt, G, Y1);
    canon_kernel<<<dim3(1024), blk, 0, stream>>>(Y1, arena + OFF_CW, arena + OFF_CB, Y2);
    // output projection (fp32 out)
    gemm_bt_kernel<<<dim3(256), blk, 0, stream>>>(Y2, WoB, d_out, 1024, 1);
}

// Round 11
// 227.198 us; speedup vs baseline: 1.0585x; 1.0170x over previous
//
#include <hip/hip_runtime.h>
#include <hip/hip_bf16.h>
#include <cstdint>

// B=2, T=2048, C=1024, H=16, HD=64, M=256, S=2560. fp32 inputs (proven R3-R6).

typedef __bf16 bf16x8_t __attribute__((ext_vector_type(8)));
typedef __bf16 bf16x4_t __attribute__((ext_vector_type(4)));
typedef float f32x4_t __attribute__((ext_vector_type(4)));

__device__ __forceinline__ f32x4_t mfma16(bf16x8_t a, bf16x8_t b, f32x4_t c) {
    return __builtin_amdgcn_mfma_f32_16x16x32_bf16(a, b, c, 0, 0, 0);
}

__device__ __forceinline__ void gl2lds16(const void* g, void* l) {
    __builtin_amdgcn_global_load_lds(
        (__attribute__((address_space(1))) uint32_t*)(uintptr_t)g,
        (__attribute__((address_space(3))) uint32_t*)l, 16, 0, 0);
}

// arena element offsets (bf16), in setup_inputs order; total 9458704
#define OFF_X   0
#define OFF_FWD 4194304
#define OFF_REV 4718592
#define OFF_WQ  5242880
#define OFF_WK  6291456
#define OFF_WV  7340032
#define OFF_WO  8388608
#define OFF_GW  9437184
#define OFF_GB  9453568
#define OFF_CW  9453584
#define OFF_CB  9457680
#define N_TOT   9458704

// ---------------------------------------------------------------------------
// Fused convert: all 11 fp32 inputs -> one contiguous bf16 arena.
// ---------------------------------------------------------------------------
__global__ __launch_bounds__(256) void conv_all_kernel(
    const void* p0, const void* p1, const void* p2, const void* p3,
    const void* p4, const void* p5, const void* p6, const void* p7,
    const void* p8, const void* p9, const void* p10,
    __hip_bfloat16* __restrict__ arena)
{
    const int i = (blockIdx.x * 256 + threadIdx.x) * 4;
    if (i >= N_TOT) return;
    const void* src; int off;
    if      (i < OFF_FWD) { src = p0;  off = OFF_X;   }
    else if (i < OFF_REV) { src = p1;  off = OFF_FWD; }
    else if (i < OFF_WQ)  { src = p2;  off = OFF_REV; }
    else if (i < OFF_WK)  { src = p3;  off = OFF_WQ;  }
    else if (i < OFF_WV)  { src = p4;  off = OFF_WK;  }
    else if (i < OFF_WO)  { src = p5;  off = OFF_WV;  }
    else if (i < OFF_GW)  { src = p6;  off = OFF_WO;  }
    else if (i < OFF_GB)  { src = p7;  off = OFF_GW;  }
    else if (i < OFF_CW)  { src = p8;  off = OFF_GB;  }
    else if (i < OFF_CB)  { src = p9;  off = OFF_CW;  }
    else                  { src = p10; off = OFF_CB;  }
    const int j = i - off;
    const float4 f = *(const float4*)((const float*)src + j);
    arena[i + 0] = __float2bfloat16(f.x);
    arena[i + 1] = __float2bfloat16(f.y);
    arena[i + 2] = __float2bfloat16(f.z);
    arena[i + 3] = __float2bfloat16(f.w);
}

// ---------------------------------------------------------------------------
// GEMM core: C[m][n] = sum_k A[m][k]*B[n][k]; K=1024. 128x128 tile, BK=32,
// 256 threads, DOUBLE-BUFFERED LDS.
// ---------------------------------------------------------------------------
__device__ __forceinline__ void gemm_core(
    const __hip_bfloat16* __restrict__ A, const __hip_bfloat16* __restrict__ B,
    void* __restrict__ C, int ldc, int f32o, int arow0, int brow0,
    __hip_bfloat16* As, __hip_bfloat16* Bs)   // each 2*128*32 elems
{
    const int tid  = threadIdx.x;
    const int lane = tid & 63;
    const int wid  = tid >> 6;
    const int q4   = lane >> 4;
    const int c16  = lane & 15;
    const int wm   = (wid >> 1) * 64;
    const int wn   = (wid & 1) * 64;
    const int c0 = tid;
    const int c1 = tid + 256;
    const __hip_bfloat16* gA0 = A + (size_t)(arow0 + (c0 >> 2)) * 1024 + ((c0 & 3) << 3);
    const __hip_bfloat16* gA1 = A + (size_t)(arow0 + (c1 >> 2)) * 1024 + ((c1 & 3) << 3);
    const __hip_bfloat16* gB0 = B + (size_t)(brow0 + (c0 >> 2)) * 1024 + ((c0 & 3) << 3);
    const __hip_bfloat16* gB1 = B + (size_t)(brow0 + (c1 >> 2)) * 1024 + ((c1 & 3) << 3);

    f32x4_t acc[4][4];
#pragma unroll
    for (int i = 0; i < 4; ++i)
#pragma unroll
        for (int j = 0; j < 4; ++j)
#pragma unroll
            for (int r = 0; r < 4; ++r) acc[i][j][r] = 0.0f;

    // prologue: stage K-step 0 into buffer 0
    gl2lds16(gA0, As + c0 * 8);
    gl2lds16(gA1, As + c1 * 8);
    gl2lds16(gB0, Bs + c0 * 8);
    gl2lds16(gB1, Bs + c1 * 8);

    for (int it = 0; it < 32; ++it) {
        __hip_bfloat16* curA = As + (it & 1) * 4096;
        __hip_bfloat16* curB = Bs + (it & 1) * 4096;
        __syncthreads();            // drains buffer(it) loads; prev reads done
        if (it < 31) {              // prefetch buffer(it+1) BEFORE compute
            const int nk = (it + 1) * 32;
            __hip_bfloat16* nA = As + ((it + 1) & 1) * 4096;
            __hip_bfloat16* nB = Bs + ((it + 1) & 1) * 4096;
            gl2lds16(gA0 + nk, nA + c0 * 8);
            gl2lds16(gA1 + nk, nA + c1 * 8);
            gl2lds16(gB0 + nk, nB + c0 * 8);
            gl2lds16(gB1 + nk, nB + c1 * 8);
        }
        bf16x8_t af[4], bfr[4];
#pragma unroll
        for (int i = 0; i < 4; ++i)
            af[i] = *(const bf16x8_t*)&curA[(wm + i * 16 + c16) * 32 + q4 * 8];
#pragma unroll
        for (int j = 0; j < 4; ++j)
            bfr[j] = *(const bf16x8_t*)&curB[(wn + j * 16 + c16) * 32 + q4 * 8];
#pragma unroll
        for (int i = 0; i < 4; ++i)
#pragma unroll
            for (int j = 0; j < 4; ++j)
                acc[i][j] = mfma16(af[i], bfr[j], acc[i][j]);
    }
#pragma unroll
    for (int i = 0; i < 4; ++i) {
        const int mg = arow0 + wm + i * 16 + q4 * 4;
#pragma unroll
        for (int j = 0; j < 4; ++j) {
            const int ng = brow0 + wn + j * 16 + c16;
#pragma unroll
            for (int r = 0; r < 4; ++r) {
                const size_t idx = (size_t)(mg + r) * ldc + ng;
                if (f32o) ((float*)C)[idx] = acc[i][j][r];
                else ((__hip_bfloat16*)C)[idx] = __float2bfloat16(acc[i][j][r]);
            }
        }
    }
}

// Fused QK + V^T launch: 896 uniform-cost blocks (each 128x128xK=1024).
// XCD-aware swizzle (T1): id=(bx&7)*112+(bx>>3).
// Q-trim: Q columns for memory rows (4096..5119) are never read.
//   id <  512: QK x-rows:   arow 0..31,  brow 0..15 (full Q+K cols)
//   id <  576: QK mem-rows: arow 32..39, brow 8..15 (K cols only)
//   else     : Vt = Wv @ [x;fwd;rev]^T  (1024x5120,  8x40 tiles)
__global__ __launch_bounds__(256) void qkv_kernel(
    const __hip_bfloat16* __restrict__ x, const __hip_bfloat16* __restrict__ Wqk,
    const __hip_bfloat16* __restrict__ Wv,
    __hip_bfloat16* __restrict__ QK, __hip_bfloat16* __restrict__ Vt)
{
    __shared__ __align__(16) __hip_bfloat16 As[2 * 128 * 32];
    __shared__ __align__(16) __hip_bfloat16 Bs[2 * 128 * 32];
    int id = (blockIdx.x & 7) * 112 + (blockIdx.x >> 3);   // XCD swizzle
    if (id < 512)
        gemm_core(x, Wqk, QK, 2048, 0, (id >> 4) * 128, (id & 15) * 128, As, Bs);
    else if (id < 576) {
        id -= 512;
        gemm_core(x, Wqk, QK, 2048, 0, (32 + (id >> 3)) * 128, (8 + (id & 7)) * 128, As, Bs);
    } else {
        id -= 576;
        gemm_core(Wv, x, Vt, 5120, 0, (id & 7) * 128, (id >> 3) * 128, As, Bs);
    }
}

// 1D grid (256) + XCD swizzle: each XCD owns one brow panel of Wo.
__global__ __launch_bounds__(256) void gemm_bt_kernel(
    const __hip_bfloat16* __restrict__ A, const __hip_bfloat16* __restrict__ B,
    void* __restrict__ C, int ldc, int f32o)
{
    __shared__ __align__(16) __hip_bfloat16 As[2 * 128 * 32];
    __shared__ __align__(16) __hip_bfloat16 Bs[2 * 128 * 32];
    const int swz = (blockIdx.x & 7) * 32 + (blockIdx.x >> 3);  // XCD swizzle
    const int arow = swz & 31;
    const int brow = swz >> 5;
    gemm_core(A, B, C, ldc, f32o, arow * 128, brow * 128, As, Bs);
}

// ---------------------------------------------------------------------------
// Gate via MFMA: one wave per 16 rows; G[row][h] = sigmoid(Q.gw^T + gb)
// (one-pass Q read; fusing into attn is a proven 28 MB FETCH blowup, R16)
// ---------------------------------------------------------------------------
__global__ __launch_bounds__(64) void gate_kernel(
    const __hip_bfloat16* __restrict__ QK, const __hip_bfloat16* __restrict__ gw,
    const __hip_bfloat16* __restrict__ gb, float* __restrict__ G)
{
    const int base = blockIdx.x * 16;
    const int lane = threadIdx.x;
    const int q4   = lane >> 4;
    const int c16  = lane & 15;
    f32x4_t acc = {0.0f, 0.0f, 0.0f, 0.0f};
    const __hip_bfloat16* qrow = QK + (size_t)(base + c16) * 2048 + q4 * 8;
    const __hip_bfloat16* wrow = gw + (size_t)c16 * 1024 + q4 * 8;
#pragma unroll
    for (int kk = 0; kk < 32; ++kk) {
        const bf16x8_t a = *(const bf16x8_t*)(qrow + kk * 32);
        const bf16x8_t w = *(const bf16x8_t*)(wrow + kk * 32);
        acc = mfma16(a, w, acc);
    }
    const float bias = __bfloat162float(gb[c16]);
#pragma unroll
    for (int r = 0; r < 4; ++r) {
        const int row = base + q4 * 4 + r;
        G[(size_t)row * 16 + c16] = 1.0f / (1.0f + __expf(-(acc[r] + bias)));
    }
}

// ---------------------------------------------------------------------------
// Flash attention, R18 = R17 + COUNTED-VMCNT barrier2 (T4, m218/AITER).
// Per-thread vm issue order per tile: V(2 gl2lds) then K(t+1)(2 gl2lds),
// pinned by sched_barrier(0). barrier2 waits vmcnt(2): retires exactly the
// V pair; the K prefetch stays in flight ACROSS the barrier and is drained
// at the next tile's barrier1 (__syncthreads, vmcnt(0) -- required there
// anyway before kb ds_reads). Last tile (no prefetch): vmcnt(0) fallback,
// else vmcnt(2) would pass without V landed. lgkmcnt(0) covers Plds writes.
// Rest identical to R17 (59.5 us verified): Ks[2] dbuf + Vs + swizzled Plds
// = 32768 B, MFMA row-sums, setprio, exp2-folded scale, lb(256,4), VGPR 64.
// ---------------------------------------------------------------------------
__global__ __launch_bounds__(256, 4) void attn_kernel(
    const __hip_bfloat16* __restrict__ QK,
    const __hip_bfloat16* __restrict__ Vt,
    const float* __restrict__ G, __hip_bfloat16* __restrict__ Y)
{
    __shared__ __align__(16) __hip_bfloat16 Ks[2][64 * 64];   // 16384 B
    __shared__ __align__(16) __hip_bfloat16 Vs[64 * 64];      //  8192 B
    __shared__ __align__(16) __hip_bfloat16 Plds[4][16 * 64]; //  8192 B
    const int flat = blockIdx.x;          // 0..1023
    const int bh   = flat & 31;           // pin bh's K/V to one XCD
    const int tIdx = 31 - (flat >> 5);    // long blocks first
    const int b    = bh >> 4;
    const int h    = bh & 15;
    const int tid  = threadIdx.x;
    const int wid  = tid >> 6;
    const int lane = tid & 63;
    const int q4   = lane >> 4;
    const int c16  = lane & 15;
    const int rowbase = tIdx * 64 + wid * 16;

    const __hip_bfloat16* qrow = QK + (size_t)(b * 2048 + rowbase + c16) * 2048 + h * 64;
    const bf16x8_t qa0 = *(const bf16x8_t*)(qrow + q4 * 8);
    const bf16x8_t qa1 = *(const bf16x8_t*)(qrow + 32 + q4 * 8);

    bf16x8_t ones;
#pragma unroll
    for (int i = 0; i < 8; ++i) ones[i] = (__bf16)1.0f;

    float gate[4];
    f32x4_t acc[4];
    f32x4_t rsC = {0.0f, 0.0f, 0.0f, 0.0f};
    f32x4_t rsM = {0.0f, 0.0f, 0.0f, 0.0f};
#pragma unroll
    for (int fp = 0; fp < 4; ++fp)
#pragma unroll
        for (int r = 0; r < 4; ++r) acc[fp][r] = 0.0f;
#pragma unroll
    for (int r = 0; r < 4; ++r)
        gate[r] = G[(size_t)(b * 2048 + rowbase + q4 * 4 + r) * 16 + h];

    const int nCausal = tIdx + 1;
    const int nTiles  = nCausal + 8;
    auto kvRow = [&](int tile) -> int {
        if (tile < nCausal) return b * 2048 + tile * 64;
        const int mi = (tile - nCausal) * 64;
        return (mi < 256) ? 4096 + b * 256 + mi : 4608 + b * 256 + (mi - 256);
    };

    const int srow0 = tid >> 3,         sch0 = (tid & 7) ^ (srow0 & 7);
    const int srow1 = (tid + 256) >> 3, sch1 = (tid & 7) ^ (srow1 & 7);
    const int sw0 = (q4 ^ (c16 & 7)) * 8;
    const int sw1 = ((q4 + 4) ^ (c16 & 7)) * 8;
    const __hip_bfloat16* Kbase = QK + 1024 + h * 64;  // K cols of fused buffer

    // prologue: stage K(0) into Ks[0]
    {
        const int vr0 = kvRow(0);
        gl2lds16(Kbase + (size_t)(vr0 + srow0) * 2048 + sch0 * 8, &Ks[0][tid * 8]);
        gl2lds16(Kbase + (size_t)(vr0 + srow1) * 2048 + sch1 * 8, &Ks[0][(tid + 256) * 8]);
    }

    const float SCL = 0.18033688f;   // 0.125 * log2(e)

    for (int tile = 0; tile < nTiles; ++tile) {
        const int cur = tile & 1;
        const int vr  = kvRow(tile);
        __syncthreads();   // barrier1: vmcnt(0) drains K(tile) (issued last
                           // tile); all waves done reading Vs(tile-1)
        // V first (oldest vm entries -> retired by barrier2's vmcnt(2))
        gl2lds16(Vt + (size_t)(h * 64 + srow0) * 5120 + vr + sch0 * 8, &Vs[tid * 8]);
        gl2lds16(Vt + (size_t)(h * 64 + srow1) * 5120 + vr + sch1 * 8, &Vs[(tid + 256) * 8]);
        __builtin_amdgcn_sched_barrier(0);   // pin V-before-K issue order
        if (tile + 1 < nTiles) {
            const int nr = kvRow(tile + 1);
            gl2lds16(Kbase + (size_t)(nr + srow0) * 2048 + sch0 * 8, &Ks[cur ^ 1][tid * 8]);
            gl2lds16(Kbase + (size_t)(nr + srow1) * 2048 + sch1 * 8, &Ks[cur ^ 1][(tid + 256) * 8]);
        }
        const bool isMem  = (tile >= nCausal);
        const bool isDiag = (tile == nCausal - 1);
        bf16x8_t kb0[4], kb1[4];
#pragma unroll
        for (int f = 0; f < 4; ++f) {
            kb0[f] = *(const bf16x8_t*)&Ks[cur][(f * 16 + c16) * 64 + sw0];
            kb1[f] = *(const bf16x8_t*)&Ks[cur][(f * 16 + c16) * 64 + sw1];
        }
        f32x4_t sc[4];
        __builtin_amdgcn_s_setprio(1);
#pragma unroll
        for (int f = 0; f < 4; ++f) {
            f32x4_t z = {0.0f, 0.0f, 0.0f, 0.0f};
            z = mfma16(qa0, kb0[f], z);
            z = mfma16(qa1, kb1[f], z);
            sc[f] = z;
        }
        __builtin_amdgcn_s_setprio(0);
#pragma unroll
        for (int f = 0; f < 4; ++f)
#pragma unroll
            for (int r = 0; r < 4; ++r) {
                float p = __builtin_amdgcn_exp2f(sc[f][r] * SCL);
                if (isDiag) {
                    const int sg = f * 16 + c16;                 // s within tile
                    if (sg > wid * 16 + q4 * 4 + r) p = 0.0f;    // q within tile
                }
                if (isMem) p *= gate[r];    // gate mem contribution only
                const int prow = q4 * 4 + r;
                const int pcol = f * 16 + c16;
                Plds[wid][prow * 64 + (((pcol >> 3) ^ (prow & 7)) << 3) + (pcol & 7)] =
                    __float2bfloat16(p);
            }
        // barrier2 (counted): wait only V(tile)+LDS ops; K(t+1) stays in
        // flight across the barrier (drained at next barrier1).
        if (tile + 1 < nTiles)
            asm volatile("s_waitcnt vmcnt(2) lgkmcnt(0)" ::: "memory");
        else
            asm volatile("s_waitcnt vmcnt(0) lgkmcnt(0)" ::: "memory");
        __builtin_amdgcn_s_barrier();
        __builtin_amdgcn_sched_barrier(0);
        bf16x8_t vb0[4], vb1[4];
#pragma unroll
        for (int f = 0; f < 4; ++f) {
            vb0[f] = *(const bf16x8_t*)&Vs[(f * 16 + c16) * 64 + sw0];
            vb1[f] = *(const bf16x8_t*)&Vs[(f * 16 + c16) * 64 + sw1];
        }
        const bf16x8_t pa0 = *(const bf16x8_t*)&Plds[wid][c16 * 64 + sw0];
        const bf16x8_t pa1 = *(const bf16x8_t*)&Plds[wid][c16 * 64 + sw1];
        __builtin_amdgcn_s_setprio(1);
        if (isMem) {
            rsM = mfma16(pa0, ones, rsM);
            rsM = mfma16(pa1, ones, rsM);
        } else {
            rsC = mfma16(pa0, ones, rsC);
            rsC = mfma16(pa1, ones, rsC);
        }
#pragma unroll
        for (int fp = 0; fp < 4; ++fp) {
            acc[fp] = mfma16(pa0, vb0[fp], acc[fp]);
            acc[fp] = mfma16(pa1, vb1[fp], acc[fp]);
        }
        __builtin_amdgcn_s_setprio(0);
    }

    // denominator: rsC (ungated causal) + rsM/gate (rsM accumulated gated P)
    float inv[4];
#pragma unroll
    for (int r = 0; r < 4; ++r)
        inv[r] = gate[r] / fmaf(gate[r], rsC[r], rsM[r]);
#pragma unroll
    for (int fp = 0; fp < 4; ++fp)
#pragma unroll
        for (int r = 0; r < 4; ++r) {
            const int tg = rowbase + q4 * 4 + r;
            Y[(size_t)(b * 2048 + tg) * 1024 + h * 64 + fp * 16 + c16] =
                __float2bfloat16(acc[fp][r] * inv[r]);
        }
}

// ---------------------------------------------------------------------------
// Canon depthwise causal conv (K=4) + bias. 4 timesteps x 4 channels per
// thread -- 7 input rows loaded once produce 4 outputs (R16-verified).
// ---------------------------------------------------------------------------
__global__ __launch_bounds__(256) void canon_kernel(
    const __hip_bfloat16* __restrict__ Yin, const __hip_bfloat16* __restrict__ cw,
    const __hip_bfloat16* __restrict__ cb, __hip_bfloat16* __restrict__ Yout)
{
    const int gid = blockIdx.x * 256 + threadIdx.x;   // 0..262143
    const int cc  = (gid & 255) * 4;                  // channel chunk base
    const int t4  = ((gid >> 8) & 511) * 4;           // time chunk base
    const int b   = gid >> 17;
    const size_t base = ((size_t)(b * 2048 + t4)) * 1024 + cc;

    bf16x4_t y[7];
#pragma unroll
    for (int m = 0; m < 7; ++m) {
        if (t4 - 3 + m >= 0)
            y[m] = *(const bf16x4_t*)(Yin + base + (ptrdiff_t)(m - 3) * 1024);
        else {
            y[m][0] = (__bf16)0.0f; y[m][1] = (__bf16)0.0f;
            y[m][2] = (__bf16)0.0f; y[m][3] = (__bf16)0.0f;
        }
    }
    const bf16x8_t w01 = *(const bf16x8_t*)(cw + cc * 4);
    const bf16x8_t w23 = *(const bf16x8_t*)(cw + cc * 4 + 8);
    const bf16x4_t bb  = *(const bf16x4_t*)(cb + cc);

#pragma unroll
    for (int k = 0; k < 4; ++k) {
        float a[4];
#pragma unroll
        for (int i = 0; i < 4; ++i) a[i] = (float)y[k + 3][i] + (float)bb[i];
#pragma unroll
        for (int j = 0; j < 4; ++j) {
            a[0] += (float)y[k + j][0] * (float)w01[j];
            a[1] += (float)y[k + j][1] * (float)w01[4 + j];
            a[2] += (float)y[k + j][2] * (float)w23[j];
            a[3] += (float)y[k + j][3] * (float)w23[4 + j];
        }
        bf16x4_t o;
#pragma unroll
        for (int i = 0; i < 4; ++i) o[i] = (__bf16)a[i];
        *(bf16x4_t*)(Yout + base + (size_t)k * 1024) = o;
    }
}

// ---------------------------------------------------------------------------
extern "C" void kernel_launch(void* const* d_in, const int* in_sizes, int n_in,
                              void* d_out, int out_size, void* d_ws, size_t ws_size,
                              hipStream_t stream)
{
    char* ws = (char*)d_ws;
    const size_t MB = 1ull << 20;
    if (ws_size < 50 * MB) return;  // canary

    __hip_bfloat16* arena = (__hip_bfloat16*)ws;              // 18.05 MB
    __hip_bfloat16* QK    = (__hip_bfloat16*)(ws + 19 * MB);  // 20 MB (5120x2048)
    __hip_bfloat16* Vt    = (__hip_bfloat16*)(ws + 39 * MB);  // 10 MB (1024x5120)
    float*          G     = (float*)(ws + 49 * MB);           // 256 KB
    __hip_bfloat16* Y1    = (__hip_bfloat16*)ws;              // reuse x region
    __hip_bfloat16* Y2    = QK;                               // reuse after attention

    const dim3 blk(256);
    conv_all_kernel<<<dim3((N_TOT / 4 + 255) / 256), blk, 0, stream>>>(
        d_in[0], d_in[1], d_in[2], d_in[3], d_in[4], d_in[5], d_in[6],
        d_in[7], d_in[8], d_in[9], d_in[10], arena);

    const __hip_bfloat16* xB  = arena + OFF_X;   // [x;fwd;rev] = 5120 rows
    const __hip_bfloat16* WqB = arena + OFF_WQ;  // [Wq;Wk] = 2048 contiguous rows
    const __hip_bfloat16* WvB = arena + OFF_WV;
    const __hip_bfloat16* WoB = arena + OFF_WO;

    // fused QK (x:full, mem:K-only) + V^T in one 896-block launch
    qkv_kernel<<<dim3(896), blk, 0, stream>>>(xB, WqB, WvB, QK, Vt);
    gate_kernel<<<dim3(256), dim3(64), 0, stream>>>(QK, arena + OFF_GW, arena + OFF_GB, G);
    attn_kernel<<<dim3(1024), blk, 0, stream>>>(QK, Vt, G, Y1);
    canon_kernel<<<dim3(1024), blk, 0, stream>>>(Y1, arena + OFF_CW, arena + OFF_CB, Y2);
    // output projection (fp32 out)
    gemm_bt_kernel<<<dim3(256), blk, 0, stream>>>(Y2, WoB, d_out, 1024, 1);
}